// Round 2
// baseline (435.544 us; speedup 1.0000x reference)
//
#include <hip/hip_runtime.h>
#include <stdint.h>

// BraidCrossing: scale = mean(softmax(.), axis=-1) == 1/6 exactly => W1/b1/W2/b2/gelu dead.
// out_t = LN(LN(x_t + P_{t-1}/6) + P_{t+1}/6), P = x @ Wp^T + bp, one-sided at t=0, T-1.
// R5: fix R4's prefetch-lead bug — staging issue order now gives every load >=2 phases
// of flight before its vmcnt wait (A granules 3 phases, B 2; A is HBM-class, B L2-class).
// Waits: VMCNT(6) end-ph1 (drains A1,A3 of t, issued one full tile earlier), VMCNT(2)
// end-ph3. Epilogue store order mi->r->j so each 128B line is 4 adjacent partials.

#define B_DIM 8
#define T_DIM 2048
#define D_DIM 2048
#define M_DIM (B_DIM * T_DIM)   // 16384
#define N_DIM D_DIM             // 2048
#define K_DIM D_DIM             // 2048
#define NT (K_DIM / 64)         // 32 K-tiles

typedef __attribute__((ext_vector_type(8))) short short8;   // 8 bf16 in 4 VGPRs
typedef __attribute__((ext_vector_type(4))) float f32x4;

__device__ inline unsigned short f2bf(float f) {
    unsigned u = __float_as_uint(f);
    u += 0x7fffu + ((u >> 16) & 1u);   // RTNE
    return (unsigned short)(u >> 16);
}
__device__ inline float bf2f(unsigned u16) {
    return __uint_as_float(u16 << 16);
}
__device__ inline void unpack8(uint4 u, float* f) {
    f[0] = bf2f(u.x & 0xffffu); f[1] = bf2f(u.x >> 16);
    f[2] = bf2f(u.y & 0xffffu); f[3] = bf2f(u.y >> 16);
    f[4] = bf2f(u.z & 0xffffu); f[5] = bf2f(u.z >> 16);
    f[6] = bf2f(u.w & 0xffffu); f[7] = bf2f(u.w >> 16);
}
__device__ inline void async_ld16(const void* g, void* l) {
    __builtin_amdgcn_global_load_lds(
        (__attribute__((address_space(1))) void*)(g),
        (__attribute__((address_space(3))) void*)(l),
        16, 0, 0);
}

#define VMCNT(n) asm volatile("s_waitcnt vmcnt(" #n ")" ::: "memory")
#define LGKM0    asm volatile("s_waitcnt lgkmcnt(0)" ::: "memory")

// ---------------- cast f32 -> bf16 (x and Wp in one launch) ----------------
__global__ void cast_f32_bf16(const float* __restrict__ x, unsigned short* __restrict__ Xb,
                              const float* __restrict__ Wp, unsigned short* __restrict__ Wb,
                              int nx4, int ntot4) {
    int i = blockIdx.x * blockDim.x + threadIdx.x;
    if (i >= ntot4) return;
    const float* src; unsigned short* dst; int j;
    if (i < nx4) { src = x; dst = Xb; j = i; }
    else         { src = Wp; dst = Wb; j = i - nx4; }
    float4 f = ((const float4*)src)[j];
    ushort4 o;
    o.x = f2bf(f.x); o.y = f2bf(f.y); o.z = f2bf(f.z); o.w = f2bf(f.w);
    ((ushort4*)dst)[j] = o;
}

// ---------------- GEMM: P = Xb(MxK) @ Wb(NxK)^T + bp, bf16 in, bf16 out ----------------
// 256x256 tile, BK=64, 512 threads (8 waves, 2Mx4N), each wave 128x64 output.
// LDS: [2 dbuf][256 rows][64 cols] bf16 per matrix = 128 KiB total.
// Read-side swizzle phys_chunk = logical ^ (row&7), staged by pre-swizzling the
// per-lane GLOBAL source col; LDS dest stays linear (rule #21).
// Staging issue schedule (tile t, into buf^1):  ph0: A0,A2 | ph1: B0..B3 | ph3: A1,A3.
// In-flight invariant at tile entry: A1,A3(t).  Waits:
//   end-ph1: VMCNT(6)  (drains A1,A3 of t — issued a full tile ago)
//   end-ph3: VMCNT(2)  (drains A0,A2 [3-phase lead] + B0..B3 [2-phase lead] of t+1)

template <int PP>
__device__ __attribute__((always_inline)) inline
void mfma16(f32x4 (&acc)[8][4], const short8 (&a)[2][2], const short8 (&b)[4][2]) {
#pragma unroll
    for (int kk = 0; kk < 2; ++kk)
#pragma unroll
        for (int i = 0; i < 2; ++i)
#pragma unroll
            for (int j = 0; j < 4; ++j)
                acc[PP * 2 + i][j] = __builtin_amdgcn_mfma_f32_16x16x32_bf16(
                    a[i][kk], b[j][kk], acc[PP * 2 + i][j], 0, 0, 0);
}

__global__ __launch_bounds__(512, 2)
void gemm_bt(const unsigned short* __restrict__ Xb,
             const unsigned short* __restrict__ Wb,
             const float* __restrict__ bp,
             unsigned short* __restrict__ P)
{
    __shared__ unsigned short As[2][256 * 64];   // 64 KB
    __shared__ unsigned short Bs[2][256 * 64];   // 64 KB

    const int tid  = threadIdx.x;
    const int lane = tid & 63;
    const int wave = tid >> 6;
    const int wm = wave >> 2;            // 0..1  (M half)
    const int wn = wave & 3;             // 0..3  (N quarter)
    const int fr = lane & 15;            // fragment row
    const int lq = lane >> 4;            // k-chunk within 32-wide step
    const int xa = fr & 7;               // read-side XOR

    // XCD-bijective swizzle: nwg=512, 512%8==0.
    const int bid = blockIdx.x;
    const int swz = (bid & 7) * 64 + (bid >> 3);
    const int m0 = (swz >> 3) * 256;     // 64 M-tiles
    const int n0 = (swz & 7) * 256;      // 8 N-tiles

    // staging map: granule = 64 rows x 64 cols (8 KB) = one global_load_lds per granule.
    const int rr = tid >> 3;
    const int cc = tid & 7;
    const int lc8 = (cc ^ (rr & 7)) * 8;
    const unsigned short* Ag = Xb + (size_t)(m0 + rr) * K_DIM + lc8;
    const unsigned short* Bg = Wb + (size_t)(n0 + rr) * K_DIM + lc8;

#define STAGE_A(buf, g, k0) async_ld16(Ag + (size_t)(g) * 64 * K_DIM + (k0), \
                                       &As[buf][((g) * 64 + rr) * 64 + cc * 8])
#define STAGE_B(buf, g, k0) async_ld16(Bg + (size_t)(g) * 64 * K_DIM + (k0), \
                                       &Bs[buf][((g) * 64 + rr) * 64 + cc * 8])
#define LDA(dst, buf, p, i, kk) dst = *(const short8*)&As[buf][ \
        (wm * 128 + (p) * 32 + (i) * 16 + fr) * 64 + ((((kk) * 4 + lq) ^ xa) * 8)]
#define LDB(dst, buf, j, kk)    dst = *(const short8*)&Bs[buf][ \
        (wn * 64 + (j) * 16 + fr) * 64 + ((((kk) * 4 + lq) ^ xa) * 8)]

    f32x4 acc[8][4];
#pragma unroll
    for (int i = 0; i < 8; ++i)
#pragma unroll
        for (int j = 0; j < 4; ++j) acc[i][j] = (f32x4){0.f, 0.f, 0.f, 0.f};

    // prologue: tile 0 -> buf 0; issue so that A1,A3 are the 2 youngest.
    STAGE_A(0, 0, 0); STAGE_A(0, 2, 0);
    STAGE_B(0, 0, 0); STAGE_B(0, 1, 0); STAGE_B(0, 2, 0); STAGE_B(0, 3, 0);
    STAGE_A(0, 1, 0); STAGE_A(0, 3, 0);
    VMCNT(2);
    __builtin_amdgcn_s_barrier();

    short8 a[2][2], b[4][2];
    for (int t = 0; t < NT - 1; ++t) {
        const int cur = t & 1, nxt = cur ^ 1;
        const int kn = (t + 1) * 64;

        // ---- phase 0: all B frags + A rows [0,32); issue A0,A2(t+1) ----
        LDB(b[0][0], cur, 0, 0); LDB(b[0][1], cur, 0, 1);
        LDB(b[1][0], cur, 1, 0); LDB(b[1][1], cur, 1, 1);
        LDB(b[2][0], cur, 2, 0); LDB(b[2][1], cur, 2, 1);
        LDB(b[3][0], cur, 3, 0); LDB(b[3][1], cur, 3, 1);
        LDA(a[0][0], cur, 0, 0, 0); LDA(a[0][1], cur, 0, 0, 1);
        LDA(a[1][0], cur, 0, 1, 0); LDA(a[1][1], cur, 0, 1, 1);
        STAGE_A(nxt, 0, kn); STAGE_A(nxt, 2, kn);
        __builtin_amdgcn_s_barrier();
        LGKM0; __builtin_amdgcn_sched_barrier(0);
        __builtin_amdgcn_s_setprio(1);
        mfma16<0>(acc, a, b);
        __builtin_amdgcn_s_setprio(0);
        __builtin_amdgcn_s_barrier();

        // ---- phase 1: A rows [32,64); issue B0..B3(t+1); drain A1,A3(t) ----
        LDA(a[0][0], cur, 1, 0, 0); LDA(a[0][1], cur, 1, 0, 1);
        LDA(a[1][0], cur, 1, 1, 0); LDA(a[1][1], cur, 1, 1, 1);
        STAGE_B(nxt, 0, kn); STAGE_B(nxt, 1, kn);
        STAGE_B(nxt, 2, kn); STAGE_B(nxt, 3, kn);
        __builtin_amdgcn_s_barrier();
        LGKM0; __builtin_amdgcn_sched_barrier(0);
        __builtin_amdgcn_s_setprio(1);
        mfma16<1>(acc, a, b);
        __builtin_amdgcn_s_setprio(0);
        VMCNT(6);                       // drain A1,A3(t); keep A0,A2,B0..B3(t+1)
        __builtin_amdgcn_s_barrier();

        // ---- phase 2: A rows [64,96); no staging ----
        LDA(a[0][0], cur, 2, 0, 0); LDA(a[0][1], cur, 2, 0, 1);
        LDA(a[1][0], cur, 2, 1, 0); LDA(a[1][1], cur, 2, 1, 1);
        __builtin_amdgcn_s_barrier();
        LGKM0; __builtin_amdgcn_sched_barrier(0);
        __builtin_amdgcn_s_setprio(1);
        mfma16<2>(acc, a, b);
        __builtin_amdgcn_s_setprio(0);
        __builtin_amdgcn_s_barrier();

        // ---- phase 3: A rows [96,128); issue A1,A3(t+1); drain all but A1,A3(t+1) ----
        LDA(a[0][0], cur, 3, 0, 0); LDA(a[0][1], cur, 3, 0, 1);
        LDA(a[1][0], cur, 3, 1, 0); LDA(a[1][1], cur, 3, 1, 1);
        STAGE_A(nxt, 1, kn); STAGE_A(nxt, 3, kn);
        __builtin_amdgcn_s_barrier();
        LGKM0; __builtin_amdgcn_sched_barrier(0);
        __builtin_amdgcn_s_setprio(1);
        mfma16<3>(acc, a, b);
        __builtin_amdgcn_s_setprio(0);
        VMCNT(2);                       // drain A0,A2,B0..B3(t+1); keep A1,A3(t+1)
        __builtin_amdgcn_s_barrier();
    }

    // ---- tail tile NT-1 (buf 1), no further issues; entry in-flight: A1,A3 ----
    {
        const int cur = (NT - 1) & 1;
        LDB(b[0][0], cur, 0, 0); LDB(b[0][1], cur, 0, 1);
        LDB(b[1][0], cur, 1, 0); LDB(b[1][1], cur, 1, 1);
        LDB(b[2][0], cur, 2, 0); LDB(b[2][1], cur, 2, 1);
        LDA(a[0][0], cur, 0, 0, 0); LDA(a[0][1], cur, 0, 0, 1);
        LDA(a[1][0], cur, 0, 1, 0); LDA(a[1][1], cur, 0, 1, 1);
        LDB(b[3][0], cur, 3, 0); LDB(b[3][1], cur, 3, 1);
        __builtin_amdgcn_s_barrier();
        LGKM0; __builtin_amdgcn_sched_barrier(0);
        __builtin_amdgcn_s_setprio(1);
        mfma16<0>(acc, a, b);
        __builtin_amdgcn_s_setprio(0);
        __builtin_amdgcn_s_barrier();

        LDA(a[0][0], cur, 1, 0, 0); LDA(a[0][1], cur, 1, 0, 1);
        LDA(a[1][0], cur, 1, 1, 0); LDA(a[1][1], cur, 1, 1, 1);
        __builtin_amdgcn_s_barrier();
        LGKM0; __builtin_amdgcn_sched_barrier(0);
        __builtin_amdgcn_s_setprio(1);
        mfma16<1>(acc, a, b);
        __builtin_amdgcn_s_setprio(0);
        VMCNT(0);                       // drain A1,A3 of the last tile
        __builtin_amdgcn_s_barrier();

        LDA(a[0][0], cur, 2, 0, 0); LDA(a[0][1], cur, 2, 0, 1);
        LDA(a[1][0], cur, 2, 1, 0); LDA(a[1][1], cur, 2, 1, 1);
        __builtin_amdgcn_s_barrier();
        LGKM0; __builtin_amdgcn_sched_barrier(0);
        __builtin_amdgcn_s_setprio(1);
        mfma16<2>(acc, a, b);
        __builtin_amdgcn_s_setprio(0);
        __builtin_amdgcn_s_barrier();

        LDA(a[0][0], cur, 3, 0, 0); LDA(a[0][1], cur, 3, 0, 1);
        LDA(a[1][0], cur, 3, 1, 0); LDA(a[1][1], cur, 3, 1, 1);
        LGKM0; __builtin_amdgcn_sched_barrier(0);
        __builtin_amdgcn_s_setprio(1);
        mfma16<3>(acc, a, b);
        __builtin_amdgcn_s_setprio(0);
    }

    // epilogue: C/D layout col=lane&15, row=(lane>>4)*4+reg  [m89/m91-verified]
    // Store order mi->r->j: 4 adjacent 32B partials complete each 128B line.
    const int crow = (lane >> 4) * 4;
    const int ccol = lane & 15;
    float bpv[4];
#pragma unroll
    for (int j = 0; j < 4; ++j) bpv[j] = bp[n0 + wn * 64 + 16 * j + ccol];
#pragma unroll
    for (int mi = 0; mi < 8; ++mi) {
#pragma unroll
        for (int r = 0; r < 4; ++r) {
            size_t base = (size_t)(m0 + wm * 128 + 16 * mi + crow + r) * N_DIM
                        + n0 + wn * 64 + ccol;
#pragma unroll
            for (int j = 0; j < 4; ++j)
                P[base + 16 * j] = f2bf(acc[mi][j][r] + bpv[j]);
        }
    }
#undef STAGE_A
#undef STAGE_B
#undef LDA
#undef LDB
}

// ---------------- fused double-LayerNorm: one wave per row ----------------
__device__ __attribute__((always_inline)) inline
void ln_wave(float* v, const float* __restrict__ gamma, const float* __restrict__ beta,
             int lane) {
    float s = 0.f, q = 0.f;
#pragma unroll
    for (int i = 0; i < 32; ++i) { s += v[i]; q += v[i] * v[i]; }
#pragma unroll
    for (int off = 32; off; off >>= 1) {
        s += __shfl_xor(s, off);
        q += __shfl_xor(q, off);
    }
    const float invD = 1.0f / (float)D_DIM;
    const float mu = s * invD;
    const float rs = rsqrtf(q * invD - mu * mu + 1e-5f);
    const float4* g4 = (const float4*)gamma;
    const float4* b4 = (const float4*)beta;
#pragma unroll
    for (int c = 0; c < 4; ++c) {
        const int e = (c * 64 + lane) * 2;
        float4 g0 = g4[e], g1 = g4[e + 1];
        float4 b0 = b4[e], b1 = b4[e + 1];
        v[c*8+0] = (v[c*8+0] - mu) * rs * g0.x + b0.x;
        v[c*8+1] = (v[c*8+1] - mu) * rs * g0.y + b0.y;
        v[c*8+2] = (v[c*8+2] - mu) * rs * g0.z + b0.z;
        v[c*8+3] = (v[c*8+3] - mu) * rs * g0.w + b0.w;
        v[c*8+4] = (v[c*8+4] - mu) * rs * g1.x + b1.x;
        v[c*8+5] = (v[c*8+5] - mu) * rs * g1.y + b1.y;
        v[c*8+6] = (v[c*8+6] - mu) * rs * g1.z + b1.z;
        v[c*8+7] = (v[c*8+7] - mu) * rs * g1.w + b1.w;
    }
}

__global__ __launch_bounds__(256)
void ln_kernel(const unsigned short* __restrict__ Xb,
               const unsigned short* __restrict__ P,
               const float* __restrict__ gamma,
               const float* __restrict__ beta,
               float* __restrict__ out)
{
    const int lane = threadIdx.x & 63;
    const int r = blockIdx.x * 4 + (threadIdx.x >> 6);   // one wave per row
    const int t = r & (T_DIM - 1);
    const float inv6 = 1.0f / 6.0f;

    float v[32];
    const uint4* xrow = (const uint4*)(Xb + (size_t)r * D_DIM);
#pragma unroll
    for (int c = 0; c < 4; ++c) {
        float f[8]; unpack8(xrow[c * 64 + lane], f);
#pragma unroll
        for (int jj = 0; jj < 8; ++jj) v[c * 8 + jj] = f[jj];
    }

    if (t > 0) {            // tmp_t = LN(x_t + P_{t-1}/6)
        const uint4* prow = (const uint4*)(P + (size_t)(r - 1) * D_DIM);
#pragma unroll
        for (int c = 0; c < 4; ++c) {
            float f[8]; unpack8(prow[c * 64 + lane], f);
#pragma unroll
            for (int jj = 0; jj < 8; ++jj) v[c * 8 + jj] += f[jj] * inv6;
        }
        ln_wave(v, gamma, beta, lane);
    }
    if (t < T_DIM - 1) {    // out_t = LN(tmp_t + P_{t+1}/6)
        const uint4* prow = (const uint4*)(P + (size_t)(r + 1) * D_DIM);
#pragma unroll
        for (int c = 0; c < 4; ++c) {
            float f[8]; unpack8(prow[c * 64 + lane], f);
#pragma unroll
            for (int jj = 0; jj < 8; ++jj) v[c * 8 + jj] += f[jj] * inv6;
        }
        ln_wave(v, gamma, beta, lane);
    }

    float4* orow = (float4*)(out + (size_t)r * D_DIM);
#pragma unroll
    for (int c = 0; c < 4; ++c) {
        const int e = (c * 64 + lane) * 2;
        orow[e]     = (float4){v[c*8+0], v[c*8+1], v[c*8+2], v[c*8+3]};
        orow[e + 1] = (float4){v[c*8+4], v[c*8+5], v[c*8+6], v[c*8+7]};
    }
}

extern "C" void kernel_launch(void* const* d_in, const int* in_sizes, int n_in,
                              void* d_out, int out_size, void* d_ws, size_t ws_size,
                              hipStream_t stream) {
    // inputs (setup_inputs order): x, W1, b1, W2, b2, Wp, bp, gamma, beta — W1/b1/W2/b2 dead.
    const float* x     = (const float*)d_in[0];
    const float* Wp    = (const float*)d_in[5];
    const float* bp    = (const float*)d_in[6];
    const float* gamma = (const float*)d_in[7];
    const float* beta  = (const float*)d_in[8];
    float* out = (float*)d_out;

    // workspace layout: Xb bf16 [64 MiB] | Wb bf16 [8 MiB] | P bf16 [64 MiB]
    unsigned short* Xb = (unsigned short*)d_ws;
    unsigned short* Wb = Xb + (size_t)M_DIM * K_DIM;
    unsigned short* P  = Wb + (size_t)N_DIM * K_DIM;

    const int nx4   = (M_DIM * K_DIM) / 4;            // 8388608
    const int ntot4 = nx4 + (N_DIM * K_DIM) / 4;      // + 1048576
    cast_f32_bf16<<<(ntot4 + 255) / 256, 256, 0, stream>>>(x, Xb, Wp, Wb, nx4, ntot4);

    gemm_bt<<<(M_DIM / 256) * (N_DIM / 256), 512, 0, stream>>>(Xb, Wb, bp, P);  // 512 WGs
    ln_kernel<<<M_DIM / 4, 256, 0, stream>>>(Xb, P, gamma, beta, out);
}

// Round 3
// 426.567 us; speedup vs baseline: 1.0210x; 1.0210x over previous
//
#include <hip/hip_runtime.h>
#include <stdint.h>

// BraidCrossing: scale = mean(softmax(.), axis=-1) == 1/6 exactly => W1/b1/W2/b2/gelu dead.
// out_t = LN(LN(x_t + P_{t-1}/6) + P_{t+1}/6), P = x @ Wp^T + bp, one-sided at t=0, T-1.
// R6: GEMM reverted to the proven 128x128/BK=64/XOR-swizzle kernel (R1: 134us, 1025 TF,
// occupancy 37% — beats both 256x256 1-block/CU attempts) + R5's verified epilogue
// store order (WRITE 117->65MB). LN rewritten as persistent wave-per-chunk with a
// 3-row raw-bf16 register pipeline: each P row read ONCE, gamma/beta held in regs,
// P_{t+1} prefetch overlaps LN stage 1. Cast: grid-stride 4096 blocks.

#define B_DIM 8
#define T_DIM 2048
#define D_DIM 2048
#define M_DIM (B_DIM * T_DIM)   // 16384
#define N_DIM D_DIM             // 2048
#define K_DIM D_DIM             // 2048
#define LROWS 8                 // rows per LN wave

typedef __attribute__((ext_vector_type(8))) short short8;   // 8 bf16 in 4 VGPRs
typedef __attribute__((ext_vector_type(4))) float f32x4;

__device__ inline unsigned short f2bf(float f) {
    unsigned u = __float_as_uint(f);
    u += 0x7fffu + ((u >> 16) & 1u);   // RTNE
    return (unsigned short)(u >> 16);
}
__device__ inline float bf2f(unsigned u16) {
    return __uint_as_float(u16 << 16);
}
__device__ inline void unpack8(uint4 u, float* f) {
    f[0] = bf2f(u.x & 0xffffu); f[1] = bf2f(u.x >> 16);
    f[2] = bf2f(u.y & 0xffffu); f[3] = bf2f(u.y >> 16);
    f[4] = bf2f(u.z & 0xffffu); f[5] = bf2f(u.z >> 16);
    f[6] = bf2f(u.w & 0xffffu); f[7] = bf2f(u.w >> 16);
}
__device__ inline void async_ld16(const void* g, void* l) {
    __builtin_amdgcn_global_load_lds(
        (__attribute__((address_space(1))) void*)(g),
        (__attribute__((address_space(3))) void*)(l),
        16, 0, 0);
}

// ---------------- cast f32 -> bf16 (x and Wp in one launch, grid-stride) ----------------
__global__ void cast_f32_bf16(const float* __restrict__ x, unsigned short* __restrict__ Xb,
                              const float* __restrict__ Wp, unsigned short* __restrict__ Wb,
                              int nx4, int ntot4) {
    for (int i = blockIdx.x * blockDim.x + threadIdx.x; i < ntot4;
         i += gridDim.x * blockDim.x) {
        const float* src; unsigned short* dst; int j;
        if (i < nx4) { src = x; dst = Xb; j = i; }
        else         { src = Wp; dst = Wb; j = i - nx4; }
        float4 f = ((const float4*)src)[j];
        ushort4 o;
        o.x = f2bf(f.x); o.y = f2bf(f.y); o.z = f2bf(f.z); o.w = f2bf(f.w);
        ((ushort4*)dst)[j] = o;
    }
}

// ---------------- GEMM: P = Xb(MxK) @ Wb(NxK)^T + bp, bf16 in, bf16 out ----------------
// 128x128 tile, BK=64, 256 threads (4 waves), each wave 64x64 via 4x4 mfma 16x16x32.
// LDS layout: row-major 128B rows, 16B chunks XOR-swizzled: phys = logical ^ (row&7).
__global__ void gemm_bt(const unsigned short* __restrict__ Xb,
                        const unsigned short* __restrict__ Wb,
                        const float* __restrict__ bp,
                        unsigned short* __restrict__ P)
{
    __shared__ unsigned short As[128 * 64];   // 16 KB
    __shared__ unsigned short Bs[128 * 64];   // 16 KB

    const int tid  = threadIdx.x;
    const int lane = tid & 63;
    const int wave = tid >> 6;
    const int m0 = blockIdx.y * 128;
    const int n0 = blockIdx.x * 128;

    // compute map
    const int rw = (wave >> 1) * 64;
    const int cw = (wave & 1) * 64;
    const int fr = lane & 15;            // fragment m (A) / n (B)
    const int lq = lane >> 4;            // 0..3 -> logical k-chunk within half

    // staging: instr (wave, q): chunk index ci = (wave*4+q)*64 + lane; 16B chunks,
    // row = ci>>3 (8 chunks/row), phys col = ci&7, logical col = phys ^ (row&7).
    int s_r[4], s_l[4], s_ci[4];
#pragma unroll
    for (int q = 0; q < 4; q++) {
        int ci = (wave * 4 + q) * 64 + lane;
        s_ci[q] = ci;
        s_r[q] = ci >> 3;
        s_l[q] = (ci & 7) ^ (s_r[q] & 7);
    }

    f32x4 acc[4][4];
#pragma unroll
    for (int i = 0; i < 4; i++)
#pragma unroll
        for (int j = 0; j < 4; j++) acc[i][j] = (f32x4){0.f, 0.f, 0.f, 0.f};

    for (int k0 = 0; k0 < K_DIM; k0 += 64) {
#pragma unroll
        for (int q = 0; q < 4; q++) {
            async_ld16(Xb + (size_t)(m0 + s_r[q]) * K_DIM + k0 + s_l[q] * 8,
                       As + s_ci[q] * 8);
            async_ld16(Wb + (size_t)(n0 + s_r[q]) * K_DIM + k0 + s_l[q] * 8,
                       Bs + s_ci[q] * 8);
        }
        __syncthreads();

#pragma unroll
        for (int kk = 0; kk < 2; kk++) {          // two 32-wide k sub-steps
            const int l = kk * 4 + lq;            // logical chunk 0..7
            short8 a[4], b[4];
#pragma unroll
            for (int i = 0; i < 4; i++) {
                int row = rw + 16 * i + fr;
                a[i] = *(const short8*)(As + row * 64 + (l ^ (row & 7)) * 8);
            }
#pragma unroll
            for (int j = 0; j < 4; j++) {
                int row = cw + 16 * j + fr;
                b[j] = *(const short8*)(Bs + row * 64 + (l ^ (row & 7)) * 8);
            }
#pragma unroll
            for (int i = 0; i < 4; i++)
#pragma unroll
                for (int j = 0; j < 4; j++)
                    acc[i][j] = __builtin_amdgcn_mfma_f32_16x16x32_bf16(a[i], b[j], acc[i][j], 0, 0, 0);
        }
        __syncthreads();
    }

    // epilogue: C/D layout col=lane&15, row=(lane>>4)*4+reg  [m89/m91-verified]
    // Store order i->r->j: the 4 partials of each 128B line are adjacent instructions
    // (R5-verified: WRITE_SIZE 117->65.5MB).
    const int crow = (lane >> 4) * 4;
    const int ccol = lane & 15;
    float bpv[4];
#pragma unroll
    for (int j = 0; j < 4; j++) bpv[j] = bp[n0 + cw + 16 * j + ccol];
#pragma unroll
    for (int i = 0; i < 4; i++) {
#pragma unroll
        for (int r = 0; r < 4; r++) {
            size_t base = (size_t)(m0 + rw + 16 * i + crow + r) * N_DIM
                        + n0 + cw + ccol;
#pragma unroll
            for (int j = 0; j < 4; j++)
                P[base + 16 * j] = f2bf(acc[i][j][r] + bpv[j]);
        }
    }
}

// ---------------- fused double-LayerNorm: persistent wave-per-chunk ----------------
__device__ __attribute__((always_inline)) inline
void ln_wave(float (&v)[32], const float (&g)[32], const float (&be)[32], int lane) {
    float s = 0.f, q = 0.f;
#pragma unroll
    for (int i = 0; i < 32; ++i) { s += v[i]; q += v[i] * v[i]; }
#pragma unroll
    for (int off = 32; off; off >>= 1) {
        s += __shfl_xor(s, off);
        q += __shfl_xor(q, off);
    }
    const float invD = 1.0f / (float)D_DIM;
    const float mu = s * invD;
    const float rs = rsqrtf(q * invD - mu * mu + 1e-5f);
#pragma unroll
    for (int i = 0; i < 32; ++i) v[i] = (v[i] - mu) * rs * g[i] + be[i];
}

__global__ __launch_bounds__(256, 2)
void ln_kernel(const unsigned short* __restrict__ Xb,
               const unsigned short* __restrict__ P,
               const float* __restrict__ gamma,
               const float* __restrict__ beta,
               float* __restrict__ out)
{
    const int lane = threadIdx.x & 63;
    const int w = blockIdx.x * 4 + (threadIdx.x >> 6);   // wave id, 0..2047
    const int r0 = w * LROWS;                             // chunk start row
    const int t0 = r0 & (T_DIM - 1);                      // chunks never cross batches
    const float inv6 = 1.0f / 6.0f;

    // gamma/beta resident in registers for the whole chunk (lane covers 32 elems)
    float g[32], be[32];
    {
        const float4* g4 = (const float4*)gamma;
        const float4* b4 = (const float4*)beta;
#pragma unroll
        for (int c = 0; c < 4; ++c) {
            const int e = (c * 64 + lane) * 2;
            float4 g0 = g4[e], g1 = g4[e + 1];
            float4 b0 = b4[e], b1 = b4[e + 1];
            g[c*8+0]=g0.x; g[c*8+1]=g0.y; g[c*8+2]=g0.z; g[c*8+3]=g0.w;
            g[c*8+4]=g1.x; g[c*8+5]=g1.y; g[c*8+6]=g1.z; g[c*8+7]=g1.w;
            be[c*8+0]=b0.x; be[c*8+1]=b0.y; be[c*8+2]=b0.z; be[c*8+3]=b0.w;
            be[c*8+4]=b1.x; be[c*8+5]=b1.y; be[c*8+6]=b1.z; be[c*8+7]=b1.w;
        }
    }

    // raw bf16 P-row pipeline: pm = P_{t-1}, pc = P_t, pn = P_{t+1} (16B/lane each)
    const uint4* Pq = (const uint4*)P;     // 256 uint4 per row
    uint4 pm[4], pc[4], pn[4];
    {
        const int rm = (t0 > 0) ? r0 - 1 : r0;   // dummy-safe at t0==0 (unused)
#pragma unroll
        for (int c = 0; c < 4; ++c) pm[c] = Pq[(size_t)rm * 256 + c * 64 + lane];
#pragma unroll
        for (int c = 0; c < 4; ++c) pc[c] = Pq[(size_t)r0 * 256 + c * 64 + lane];
    }

    for (int tt = 0; tt < LROWS; ++tt) {
        const int r = r0 + tt;
        const int t = t0 + tt;

        // prefetch P_{t+1} (clamped dummy at t==T-1, unused) — overlaps LN stage 1
        const int rn = (t < T_DIM - 1) ? r + 1 : r;
#pragma unroll
        for (int c = 0; c < 4; ++c) pn[c] = Pq[(size_t)rn * 256 + c * 64 + lane];

        // x row
        float v[32];
        const uint4* xq = (const uint4*)Xb + (size_t)r * 256;
#pragma unroll
        for (int c = 0; c < 4; ++c) {
            float f[8]; unpack8(xq[c * 64 + lane], f);
#pragma unroll
            for (int jj = 0; jj < 8; ++jj) v[c * 8 + jj] = f[jj];
        }

        if (t > 0) {            // tmp_t = LN(x_t + P_{t-1}/6)
#pragma unroll
            for (int c = 0; c < 4; ++c) {
                float f[8]; unpack8(pm[c], f);
#pragma unroll
                for (int jj = 0; jj < 8; ++jj) v[c * 8 + jj] += f[jj] * inv6;
            }
            ln_wave(v, g, be, lane);
        }
        if (t < T_DIM - 1) {    // out_t = LN(tmp_t + P_{t+1}/6)
#pragma unroll
            for (int c = 0; c < 4; ++c) {
                float f[8]; unpack8(pn[c], f);
#pragma unroll
                for (int jj = 0; jj < 8; ++jj) v[c * 8 + jj] += f[jj] * inv6;
            }
            ln_wave(v, g, be, lane);
        }

        float4* orow = (float4*)(out + (size_t)r * D_DIM);
#pragma unroll
        for (int c = 0; c < 4; ++c) {
            const int e = (c * 64 + lane) * 2;
            orow[e]     = (float4){v[c*8+0], v[c*8+1], v[c*8+2], v[c*8+3]};
            orow[e + 1] = (float4){v[c*8+4], v[c*8+5], v[c*8+6], v[c*8+7]};
        }

        // shift pipeline
#pragma unroll
        for (int c = 0; c < 4; ++c) { pm[c] = pc[c]; pc[c] = pn[c]; }
    }
}

extern "C" void kernel_launch(void* const* d_in, const int* in_sizes, int n_in,
                              void* d_out, int out_size, void* d_ws, size_t ws_size,
                              hipStream_t stream) {
    // inputs (setup_inputs order): x, W1, b1, W2, b2, Wp, bp, gamma, beta — W1/b1/W2/b2 dead.
    const float* x     = (const float*)d_in[0];
    const float* Wp    = (const float*)d_in[5];
    const float* bp    = (const float*)d_in[6];
    const float* gamma = (const float*)d_in[7];
    const float* beta  = (const float*)d_in[8];
    float* out = (float*)d_out;

    // workspace layout: Xb bf16 [64 MiB] | Wb bf16 [8 MiB] | P bf16 [64 MiB]
    unsigned short* Xb = (unsigned short*)d_ws;
    unsigned short* Wb = Xb + (size_t)M_DIM * K_DIM;
    unsigned short* P  = Wb + (size_t)N_DIM * K_DIM;

    const int nx4   = (M_DIM * K_DIM) / 4;            // 8388608
    const int ntot4 = nx4 + (N_DIM * K_DIM) / 4;      // + 1048576
    cast_f32_bf16<<<4096, 256, 0, stream>>>(x, Xb, Wp, Wb, nx4, ntot4);

    dim3 ggrid(N_DIM / 128, M_DIM / 128);  // (16, 128)
    gemm_bt<<<ggrid, 256, 0, stream>>>(Xb, Wb, bp, P);

    ln_kernel<<<(M_DIM / LROWS) / 4, 256, 0, stream>>>(Xb, P, gamma, beta, out);  // 512 blocks
}